// Round 6
// baseline (88.080 us; speedup 1.0000x reference)
//
#include <hip/hip_runtime.h>
#include <hip/hip_bf16.h>

#define B_ROWS 4096
#define C_CLS  1000
#define D_DIM  2048
#define NPAD   1024

typedef __attribute__((ext_vector_type(8))) short s16x8;
typedef __attribute__((ext_vector_type(4))) float f32x4;

__device__ __forceinline__ unsigned short f2bf(float f) {
    __hip_bfloat16 h = __float2bfloat16(f);
    unsigned short u;
    __builtin_memcpy(&u, &h, 2);
    return u;
}

// Kernel 1: W (1000x2048 fp32) -> Wb (1024x2048 bf16, padded rows zero) + sq_w fp32
__global__ __launch_bounds__(256) void prep_kernel(const float* __restrict__ W,
                                                   unsigned short* __restrict__ Wb,
                                                   float* __restrict__ sqw) {
    const int row = blockIdx.x;
    const int tid = threadIdx.x;
    unsigned short* wrow = Wb + (size_t)row * D_DIM;
    if (row >= C_CLS) {
        uint4 z; z.x = z.y = z.z = z.w = 0u;
        *reinterpret_cast<uint4*>(wrow + tid * 8) = z;
        if (tid == 0) sqw[row] = 0.f;
        return;
    }
    const float* wr = W + (size_t)row * D_DIM;
    float4 x0 = *reinterpret_cast<const float4*>(wr + tid * 8);
    float4 x1 = *reinterpret_cast<const float4*>(wr + tid * 8 + 4);
    float s = x0.x * x0.x + x0.y * x0.y + x0.z * x0.z + x0.w * x0.w
            + x1.x * x1.x + x1.y * x1.y + x1.z * x1.z + x1.w * x1.w;
    union { unsigned short u[8]; uint4 v; } pk;
    pk.u[0] = f2bf(x0.x); pk.u[1] = f2bf(x0.y); pk.u[2] = f2bf(x0.z); pk.u[3] = f2bf(x0.w);
    pk.u[4] = f2bf(x1.x); pk.u[5] = f2bf(x1.y); pk.u[6] = f2bf(x1.z); pk.u[7] = f2bf(x1.w);
    *reinterpret_cast<uint4*>(wrow + tid * 8) = pk.v;
#pragma unroll
    for (int off = 32; off > 0; off >>= 1) s += __shfl_down(s, off);
    __shared__ float sv[4];
    const int lane = tid & 63, wid = tid >> 6;
    if (lane == 0) sv[wid] = s;
    __syncthreads();
    if (tid == 0) sqw[row] = sv[0] + sv[1] + sv[2] + sv[3];
}

// Kernel 2: dist[a][c] = k * sqrt(max(sq[a]+sq[c]-2*Wb[a].Wb[c], 0))
// Staged GEMM, T4 counted-vmcnt depth-3 pipeline (4 LDS buffers) + K-SPLIT waves
// to cut LDS-read amplification (the measured bottleneck: ds_read_b128 pipe):
//   8 waves = 2 k-halves x (2x2) 32x32 sub-tiles. Each wave reads only 4
//   ds_read_b128 per step (a0,a1,b0,b1 of ITS k-half) and does 4 MFMAs ->
//   32 KB/step LDS reads (vs 48 before). K-partials summed via LDS at the end.
//   global_load_lds width-16 staging; 16B-granule XOR swizzle on BOTH sides
//   (pre-swizzled global source + swizzled ds_read) per rule #21.
__global__ __launch_bounds__(512) void dist_kernel(const unsigned short* __restrict__ Wb,
                                                   const float* __restrict__ sqw,
                                                   const float* __restrict__ Kin,
                                                   float* __restrict__ dist) {
    __shared__ unsigned short smem[4][2][64 * 64];   // [buf][A/B][row*64+col], 64 KB

    const int tid  = threadIdx.x;
    const int lane = tid & 63;
    const int wid  = tid >> 6;        // 0..7
    const int ksl  = wid >> 2;        // 0..1  (k-half owned by this wave)
    const int wsub = wid & 3;
    const int wm   = wsub >> 1;       // 0..1  (32-row strip)
    const int wn   = wsub & 1;        // 0..1  (32-col strip)
    const int l16  = lane & 15;
    const int quad = lane >> 4;       // 0..3

    // XCD-locality swizzle: 8 regions of 4(by) x 8(bx) tiles; XCD key = blockIdx & 7
    const int b  = blockIdx.x;
    const int rg = b & 7, s = b >> 3;
    const int by = (rg >> 1) * 4 + (s >> 3);   // 0..15
    const int bx = (rg & 1) * 8 + (s & 7);     // 0..15

    // staging: wave wid covers tile rows [wid*8, wid*8+8), 64 cols (128 B) per k-step.
    // LDS dest linear (wave base + lane*16); XOR swizzle (byte ^= (row&7)<<4)
    // realized by permuting the GLOBAL source granule: (lane&7) ^ (lane>>3).
    const int srow = wid * 8 + (lane >> 3);
    const int scol = (((lane & 7) ^ (lane >> 3)) << 3);   // elements (granule*8)
    const unsigned short* gA = Wb + (size_t)(by * 64 + srow) * D_DIM + scol;
    const unsigned short* gB = Wb + (size_t)(bx * 64 + srow) * D_DIM + scol;

#define STAGE(bufi, kk)                                                                 \
    do {                                                                                \
        __builtin_amdgcn_global_load_lds(                                               \
            (const __attribute__((address_space(1))) void*)(gA + (kk)),                 \
            (__attribute__((address_space(3))) void*)&smem[bufi][0][wid * 512], 16, 0, 0); \
        __builtin_amdgcn_global_load_lds(                                               \
            (const __attribute__((address_space(1))) void*)(gB + (kk)),                 \
            (__attribute__((address_space(3))) void*)&smem[bufi][1][wid * 512], 16, 0, 0); \
    } while (0)

    f32x4 acc00 = {0.f, 0.f, 0.f, 0.f};
    f32x4 acc01 = {0.f, 0.f, 0.f, 0.f};
    f32x4 acc10 = {0.f, 0.f, 0.f, 0.f};
    f32x4 acc11 = {0.f, 0.f, 0.f, 0.f};

    STAGE(0, 0);
    STAGE(1, 64);
    STAGE(2, 128);

    // swizzled read addressing (constant per thread):
    // rows offset by 0/16/32/48 from l16 keep row&7 == lane&7.
    const int arow0 = (wm * 32 + l16) * 64;
    const int arow1 = (wm * 32 + 16 + l16) * 64;
    const int brow0 = (wn * 32 + l16) * 64;
    const int brow1 = (wn * 32 + 16 + l16) * 64;
    const int cs = (((ksl * 4 + quad) ^ (lane & 7)) << 3);   // granule*8 elements

    for (int t = 0; t < 32; ++t) {
        // wait own S(t) only; keep deeper prefetches in flight
        if (t < 30)       asm volatile("s_waitcnt vmcnt(4)" ::: "memory");
        else if (t == 30) asm volatile("s_waitcnt vmcnt(2)" ::: "memory");
        else              asm volatile("s_waitcnt vmcnt(0)" ::: "memory");
        __builtin_amdgcn_s_barrier();
        asm volatile("" ::: "memory");

        if (t < 29) STAGE((t + 3) & 3, (t + 3) * 64);   // into slot (t-1)&3: free now

        const unsigned short* Ab = &smem[t & 3][0][0];
        const unsigned short* Bb = &smem[t & 3][1][0];
        s16x8 a0 = *reinterpret_cast<const s16x8*>(Ab + arow0 + cs);
        s16x8 a1 = *reinterpret_cast<const s16x8*>(Ab + arow1 + cs);
        s16x8 b0 = *reinterpret_cast<const s16x8*>(Bb + brow0 + cs);
        s16x8 b1 = *reinterpret_cast<const s16x8*>(Bb + brow1 + cs);
        acc00 = __builtin_amdgcn_mfma_f32_16x16x32_bf16(a0, b0, acc00, 0, 0, 0);
        acc01 = __builtin_amdgcn_mfma_f32_16x16x32_bf16(a0, b1, acc01, 0, 0, 0);
        acc10 = __builtin_amdgcn_mfma_f32_16x16x32_bf16(a1, b0, acc10, 0, 0, 0);
        acc11 = __builtin_amdgcn_mfma_f32_16x16x32_bf16(a1, b1, acc11, 0, 0, 0);
    }
#undef STAGE

    // sum k-split partials across wave pairs (wid, wid+4) via LDS (reuse smem)
    __syncthreads();
    float* fs = reinterpret_cast<float*>(&smem[0][0][0]);
    if (wid >= 4) {
        float* dst = fs + (size_t)(wid - 4) * 1024 + lane * 16;
        *reinterpret_cast<f32x4*>(dst + 0)  = acc00;
        *reinterpret_cast<f32x4*>(dst + 4)  = acc01;
        *reinterpret_cast<f32x4*>(dst + 8)  = acc10;
        *reinterpret_cast<f32x4*>(dst + 12) = acc11;
    }
    __syncthreads();
    if (wid < 4) {
        const float* src = fs + (size_t)wid * 1024 + lane * 16;
        acc00 += *reinterpret_cast<const f32x4*>(src + 0);
        acc01 += *reinterpret_cast<const f32x4*>(src + 4);
        acc10 += *reinterpret_cast<const f32x4*>(src + 8);
        acc11 += *reinterpret_cast<const f32x4*>(src + 12);

        const float kscale = Kin[0] * 4.4642857142857144f;  // 1/0.224 (DATA_SCALING)
        f32x4 accs[2][2] = {{acc00, acc01}, {acc10, acc11}};
#pragma unroll
        for (int mt = 0; mt < 2; ++mt) {
#pragma unroll
            for (int nt = 0; nt < 2; ++nt) {
#pragma unroll
                for (int r = 0; r < 4; ++r) {
                    const int ga = by * 64 + wm * 32 + mt * 16 + quad * 4 + r;
                    const int gc = bx * 64 + wn * 32 + nt * 16 + l16;
                    float d2 = sqw[ga] + sqw[gc] - 2.0f * accs[mt][nt][r];
                    dist[(size_t)ga * NPAD + gc] = kscale * sqrtf(fmaxf(d2, 0.f));
                }
            }
        }
    }
}

// Kernel 3: per row of prediction: argmax (lowest-index tie-break) then min ratio
__global__ __launch_bounds__(256) void final_kernel(const float* __restrict__ pred,
                                                    const float* __restrict__ dist,
                                                    float* __restrict__ out) {
    const int row = blockIdx.x;
    const int tid = threadIdx.x;
    const int lane = tid & 63, wid = tid >> 6;
    __shared__ float sp[C_CLS];
    __shared__ float sv[4];
    __shared__ int   si[4];

    const float* p = pred + (size_t)row * C_CLS;
    float v = -INFINITY;
    int bi = 0x7fffffff;
    if (tid < 250) {  // 250*4 = 1000, 16B aligned (row stride 4000 B is 16B-multiple)
        float4 x = *reinterpret_cast<const float4*>(p + tid * 4);
        const int c0 = tid * 4;
        sp[c0 + 0] = x.x; sp[c0 + 1] = x.y; sp[c0 + 2] = x.z; sp[c0 + 3] = x.w;
        v = x.x; bi = c0;
        if (x.y > v) { v = x.y; bi = c0 + 1; }
        if (x.z > v) { v = x.z; bi = c0 + 2; }
        if (x.w > v) { v = x.w; bi = c0 + 3; }
    }
#pragma unroll
    for (int off = 32; off > 0; off >>= 1) {
        float ov = __shfl_down(v, off);
        int   oi = __shfl_down(bi, off);
        if (ov > v || (ov == v && oi < bi)) { v = ov; bi = oi; }
    }
    if (lane == 0) { sv[wid] = v; si[wid] = bi; }
    __syncthreads();
    float y0 = sv[0]; int j0 = si[0];
#pragma unroll
    for (int w = 1; w < 4; ++w) {
        if (sv[w] > y0 || (sv[w] == y0 && si[w] < j0)) { y0 = sv[w]; j0 = si[w]; }
    }

    const float* drow = dist + (size_t)j0 * NPAD;
    float rmin = INFINITY;
    if (tid < 250) {
        const int c0 = tid * 4;
        float4 dv = *reinterpret_cast<const float4*>(drow + c0);
        float4 pv = *reinterpret_cast<const float4*>(&sp[c0]);
        // c==j0: reference uses +inf there; skip component (avoids 0*inf NaN)
        if (c0 + 0 != j0) rmin = fminf(rmin, (y0 - pv.x) * __builtin_amdgcn_rcpf(dv.x));
        if (c0 + 1 != j0) rmin = fminf(rmin, (y0 - pv.y) * __builtin_amdgcn_rcpf(dv.y));
        if (c0 + 2 != j0) rmin = fminf(rmin, (y0 - pv.z) * __builtin_amdgcn_rcpf(dv.z));
        if (c0 + 3 != j0) rmin = fminf(rmin, (y0 - pv.w) * __builtin_amdgcn_rcpf(dv.w));
    }
#pragma unroll
    for (int off = 32; off > 0; off >>= 1) rmin = fminf(rmin, __shfl_down(rmin, off));
    __syncthreads();  // all reads of sv/si for argmax done before reuse
    if (lane == 0) sv[wid] = rmin;
    __syncthreads();
    if (tid == 0) out[row] = fminf(fminf(sv[0], sv[1]), fminf(sv[2], sv[3]));
}

extern "C" void kernel_launch(void* const* d_in, const int* in_sizes, int n_in,
                              void* d_out, int out_size, void* d_ws, size_t ws_size,
                              hipStream_t stream) {
    const float* pred = (const float*)d_in[0];   // (4096, 1000) fp32
    const float* W    = (const float*)d_in[1];   // (1000, 2048) fp32
    const float* K    = (const float*)d_in[2];   // (1,) fp32
    float* out = (float*)d_out;                  // (4096,) fp32

    char* ws = (char*)d_ws;
    unsigned short* Wb = (unsigned short*)ws;                               // 1024*2048*2 = 4 MB
    float* dist = (float*)(ws + (size_t)NPAD * D_DIM * 2);                  // 1024*1024*4 = 4 MB
    float* sqw  = (float*)(ws + (size_t)NPAD * D_DIM * 2 + (size_t)NPAD * NPAD * 4); // 4 KB

    prep_kernel<<<NPAD, 256, 0, stream>>>(W, Wb, sqw);
    dist_kernel<<<dim3(256), 512, 0, stream>>>(Wb, sqw, K, dist);
    final_kernel<<<B_ROWS, 256, 0, stream>>>(pred, dist, out);
}

// Round 7
// 85.823 us; speedup vs baseline: 1.0263x; 1.0263x over previous
//
#include <hip/hip_runtime.h>
#include <hip/hip_bf16.h>

#define B_ROWS 4096
#define C_CLS  1000
#define D_DIM  2048
#define NPAD   1024

typedef __attribute__((ext_vector_type(8))) short s16x8;
typedef __attribute__((ext_vector_type(4))) float f32x4;

__device__ __forceinline__ unsigned short f2bf(float f) {
    __hip_bfloat16 h = __float2bfloat16(f);
    unsigned short u;
    __builtin_memcpy(&u, &h, 2);
    return u;
}

// Kernel 1: W (1000x2048 fp32) -> Wb (1024x2048 bf16, padded rows zero) + sq_w fp32
__global__ __launch_bounds__(256) void prep_kernel(const float* __restrict__ W,
                                                   unsigned short* __restrict__ Wb,
                                                   float* __restrict__ sqw) {
    const int row = blockIdx.x;
    const int tid = threadIdx.x;
    unsigned short* wrow = Wb + (size_t)row * D_DIM;
    if (row >= C_CLS) {
        uint4 z; z.x = z.y = z.z = z.w = 0u;
        *reinterpret_cast<uint4*>(wrow + tid * 8) = z;
        if (tid == 0) sqw[row] = 0.f;
        return;
    }
    const float* wr = W + (size_t)row * D_DIM;
    float4 x0 = *reinterpret_cast<const float4*>(wr + tid * 8);
    float4 x1 = *reinterpret_cast<const float4*>(wr + tid * 8 + 4);
    float s = x0.x * x0.x + x0.y * x0.y + x0.z * x0.z + x0.w * x0.w
            + x1.x * x1.x + x1.y * x1.y + x1.z * x1.z + x1.w * x1.w;
    union { unsigned short u[8]; uint4 v; } pk;
    pk.u[0] = f2bf(x0.x); pk.u[1] = f2bf(x0.y); pk.u[2] = f2bf(x0.z); pk.u[3] = f2bf(x0.w);
    pk.u[4] = f2bf(x1.x); pk.u[5] = f2bf(x1.y); pk.u[6] = f2bf(x1.z); pk.u[7] = f2bf(x1.w);
    *reinterpret_cast<uint4*>(wrow + tid * 8) = pk.v;
#pragma unroll
    for (int off = 32; off > 0; off >>= 1) s += __shfl_down(s, off);
    __shared__ float sv[4];
    const int lane = tid & 63, wid = tid >> 6;
    if (lane == 0) sv[wid] = s;
    __syncthreads();
    if (tid == 0) sqw[row] = sv[0] + sv[1] + sv[2] + sv[3];
}

// Kernel 2: dot-partial GEMM. Grid 512 = 256 tiles (64x64) x 2 K-halves (K=1024).
// 512 thr x 64 KB LDS -> 2 blocks/CU resident: one block's barrier/vmcnt stall
// is hidden by the sibling block's compute (the measured ~400 cyc/step stall at
// 1 block/CU). Per-block structure identical to the verified R5 kernel:
// wave (wm 0..3, wn 0..1) owns 16x32; depth-3 counted-vmcnt pipeline (4 buffers);
// global_load_lds width-16; 16B-granule XOR swizzle on BOTH sides (rule #21).
// Output: RAW dot products into dbuf[kset] (transform moved to final_kernel).
__global__ __launch_bounds__(512) void dist_kernel(const unsigned short* __restrict__ Wb,
                                                   float* __restrict__ dbuf) {
    __shared__ unsigned short smem[4][2][64 * 64];   // [buf][A/B][row*64+col], 64 KB

    const int tid  = threadIdx.x;
    const int lane = tid & 63;
    const int wid  = tid >> 6;        // 0..7
    const int wm   = wid >> 1;        // 0..3  (16-row strip)
    const int wn   = wid & 1;         // 0..1  (32-col strip)
    const int l16  = lane & 15;
    const int quad = lane >> 4;       // 0..3

    // decode: XCD key = b&7 (8 regions of 4x8 tiles); within region: kset + tile
    const int b    = blockIdx.x;
    const int rg   = b & 7, s = b >> 3;   // s in [0,64)
    const int kset = s & 1;               // K-half
    const int tidx = s >> 1;              // 0..31
    const int by   = (rg >> 1) * 4 + (tidx >> 3);   // 0..15
    const int bx   = (rg & 1) * 8 + (tidx & 7);     // 0..15
    const int kbase = kset * 1024;

    // staging: wave wid covers tile rows [wid*8, wid*8+8), 64 cols (128 B) per step.
    // LDS dest linear; XOR swizzle (byte ^= (row&7)<<4) realized by permuting the
    // GLOBAL source granule: (lane&7) ^ (lane>>3).
    const int srow = wid * 8 + (lane >> 3);
    const int scol = (((lane & 7) ^ (lane >> 3)) << 3);   // elements (granule*8)
    const unsigned short* gA = Wb + (size_t)(by * 64 + srow) * D_DIM + kbase + scol;
    const unsigned short* gB = Wb + (size_t)(bx * 64 + srow) * D_DIM + kbase + scol;

#define STAGE(bufi, kk)                                                                 \
    do {                                                                                \
        __builtin_amdgcn_global_load_lds(                                               \
            (const __attribute__((address_space(1))) void*)(gA + (kk)),                 \
            (__attribute__((address_space(3))) void*)&smem[bufi][0][wid * 512], 16, 0, 0); \
        __builtin_amdgcn_global_load_lds(                                               \
            (const __attribute__((address_space(1))) void*)(gB + (kk)),                 \
            (__attribute__((address_space(3))) void*)&smem[bufi][1][wid * 512], 16, 0, 0); \
    } while (0)

    f32x4 acc0 = {0.f, 0.f, 0.f, 0.f};
    f32x4 acc1 = {0.f, 0.f, 0.f, 0.f};

    STAGE(0, 0);
    STAGE(1, 64);
    STAGE(2, 128);

    const int arow  = (wm * 16 + l16) * 64;
    const int brow0 = (wn * 32 + l16) * 64;
    const int brow1 = (wn * 32 + 16 + l16) * 64;

    for (int t = 0; t < 16; ++t) {
        // wait own S(t) only; keep deeper prefetches in flight
        if (t < 14)       asm volatile("s_waitcnt vmcnt(4)" ::: "memory");
        else if (t == 14) asm volatile("s_waitcnt vmcnt(2)" ::: "memory");
        else              asm volatile("s_waitcnt vmcnt(0)" ::: "memory");
        __builtin_amdgcn_s_barrier();
        asm volatile("" ::: "memory");

        if (t < 13) STAGE((t + 3) & 3, (t + 3) * 64);   // into slot (t-1)&3: free now

        const unsigned short* Ab = &smem[t & 3][0][0];
        const unsigned short* Bb = &smem[t & 3][1][0];
        s16x8 a[2], b0[2], b1[2];
#pragma unroll
        for (int ks = 0; ks < 2; ++ks) {
            // swizzled read: col-granule (ks*4+quad) ^ (row&7); row&7 == lane&7 here
            const int cs = ((((ks << 2) | quad) ^ (lane & 7)) << 3);
            a[ks]  = *reinterpret_cast<const s16x8*>(Ab + arow  + cs);
            b0[ks] = *reinterpret_cast<const s16x8*>(Bb + brow0 + cs);
            b1[ks] = *reinterpret_cast<const s16x8*>(Bb + brow1 + cs);
        }
#pragma unroll
        for (int ks = 0; ks < 2; ++ks) {
            acc0 = __builtin_amdgcn_mfma_f32_16x16x32_bf16(a[ks], b0[ks], acc0, 0, 0, 0);
            acc1 = __builtin_amdgcn_mfma_f32_16x16x32_bf16(a[ks], b1[ks], acc1, 0, 0, 0);
        }
    }
#undef STAGE

    // write raw dot partials (no transform)
    float* dst = dbuf + (size_t)kset * NPAD * NPAD;
    f32x4 accs[2] = {acc0, acc1};
#pragma unroll
    for (int nt = 0; nt < 2; ++nt) {
#pragma unroll
        for (int r = 0; r < 4; ++r) {
            const int ga = by * 64 + wm * 16 + quad * 4 + r;   // C/D: row = quad*4+reg
            const int gc = bx * 64 + wn * 32 + nt * 16 + l16;  // C/D: col = lane&15
            dst[(size_t)ga * NPAD + gc] = accs[nt][r];
        }
    }
}

// Kernel 3: per row: argmax (lowest-index tie-break), then min over c of
//   (y0 - pred[c]) / (kscale * sqrt(max(sq[j0]+sq[c]-2*(dot0+dot1), 0)))
__global__ __launch_bounds__(256) void final_kernel(const float* __restrict__ pred,
                                                    const float* __restrict__ dbuf,
                                                    const float* __restrict__ sqw,
                                                    const float* __restrict__ Kin,
                                                    float* __restrict__ out) {
    const int row = blockIdx.x;
    const int tid = threadIdx.x;
    const int lane = tid & 63, wid = tid >> 6;
    __shared__ float sp[C_CLS];
    __shared__ float sv[4];
    __shared__ int   si[4];

    const float* p = pred + (size_t)row * C_CLS;
    float v = -INFINITY;
    int bi = 0x7fffffff;
    if (tid < 250) {  // 250*4 = 1000, 16B aligned (row stride 4000 B is 16B-multiple)
        float4 x = *reinterpret_cast<const float4*>(p + tid * 4);
        const int c0 = tid * 4;
        sp[c0 + 0] = x.x; sp[c0 + 1] = x.y; sp[c0 + 2] = x.z; sp[c0 + 3] = x.w;
        v = x.x; bi = c0;
        if (x.y > v) { v = x.y; bi = c0 + 1; }
        if (x.z > v) { v = x.z; bi = c0 + 2; }
        if (x.w > v) { v = x.w; bi = c0 + 3; }
    }
#pragma unroll
    for (int off = 32; off > 0; off >>= 1) {
        float ov = __shfl_down(v, off);
        int   oi = __shfl_down(bi, off);
        if (ov > v || (ov == v && oi < bi)) { v = ov; bi = oi; }
    }
    if (lane == 0) { sv[wid] = v; si[wid] = bi; }
    __syncthreads();
    float y0 = sv[0]; int j0 = si[0];
#pragma unroll
    for (int w = 1; w < 4; ++w) {
        if (sv[w] > y0 || (sv[w] == y0 && si[w] < j0)) { y0 = sv[w]; j0 = si[w]; }
    }

    const float kscale = Kin[0] * 4.4642857142857144f;  // 1/0.224 (DATA_SCALING)
    const float inv_ks = 1.0f / kscale;
    const float sqj = sqw[j0];
    const float* d0 = dbuf + (size_t)j0 * NPAD;
    const float* d1 = dbuf + (size_t)NPAD * NPAD + (size_t)j0 * NPAD;

    float rmin = INFINITY;
    if (tid < 250) {
        const int c0 = tid * 4;
        float4 a  = *reinterpret_cast<const float4*>(d0 + c0);
        float4 b  = *reinterpret_cast<const float4*>(d1 + c0);
        float4 sq = *reinterpret_cast<const float4*>(sqw + c0);
        float4 pv = *reinterpret_cast<const float4*>(&sp[c0]);
        // c==j0: reference uses +inf there; skip component
        if (c0 + 0 != j0) {
            float d2 = sqj + sq.x - 2.0f * (a.x + b.x);
            rmin = fminf(rmin, (y0 - pv.x) * inv_ks * __builtin_amdgcn_rsqf(fmaxf(d2, 0.f)));
        }
        if (c0 + 1 != j0) {
            float d2 = sqj + sq.y - 2.0f * (a.y + b.y);
            rmin = fminf(rmin, (y0 - pv.y) * inv_ks * __builtin_amdgcn_rsqf(fmaxf(d2, 0.f)));
        }
        if (c0 + 2 != j0) {
            float d2 = sqj + sq.z - 2.0f * (a.z + b.z);
            rmin = fminf(rmin, (y0 - pv.z) * inv_ks * __builtin_amdgcn_rsqf(fmaxf(d2, 0.f)));
        }
        if (c0 + 3 != j0) {
            float d2 = sqj + sq.w - 2.0f * (a.w + b.w);
            rmin = fminf(rmin, (y0 - pv.w) * inv_ks * __builtin_amdgcn_rsqf(fmaxf(d2, 0.f)));
        }
    }
#pragma unroll
    for (int off = 32; off > 0; off >>= 1) rmin = fminf(rmin, __shfl_down(rmin, off));
    __syncthreads();  // all reads of sv/si for argmax done before reuse
    if (lane == 0) sv[wid] = rmin;
    __syncthreads();
    if (tid == 0) out[row] = fminf(fminf(sv[0], sv[1]), fminf(sv[2], sv[3]));
}

extern "C" void kernel_launch(void* const* d_in, const int* in_sizes, int n_in,
                              void* d_out, int out_size, void* d_ws, size_t ws_size,
                              hipStream_t stream) {
    const float* pred = (const float*)d_in[0];   // (4096, 1000) fp32
    const float* W    = (const float*)d_in[1];   // (1000, 2048) fp32
    const float* K    = (const float*)d_in[2];   // (1,) fp32
    float* out = (float*)d_out;                  // (4096,) fp32

    char* ws = (char*)d_ws;
    unsigned short* Wb = (unsigned short*)ws;                      // 4 MB
    float* dbuf = (float*)(ws + (size_t)NPAD * D_DIM * 2);         // 2 x 4 MB raw dot partials
    float* sqw  = (float*)(ws + (size_t)NPAD * D_DIM * 2 + 2 * (size_t)NPAD * NPAD * 4); // 4 KB

    prep_kernel<<<NPAD, 256, 0, stream>>>(W, Wb, sqw);
    dist_kernel<<<dim3(512), 512, 0, stream>>>(Wb, dbuf);   // 2 blocks/CU
    final_kernel<<<B_ROWS, 256, 0, stream>>>(pred, dbuf, sqw, K, out);
}